// Round 4
// baseline (507.507 us; speedup 1.0000x reference)
//
#include <hip/hip_runtime.h>
#include <hip/hip_bf16.h>
#include <math.h>

// Problem constants: B=4, N=4096, k=32, Cin=64, Cout=64, M=8, hidden=16
#define PB 4
#define PN 4096
#define PK 32
#define NKP (PN * PK)              // 131072 points per batch (2^17)
#define PTOT (PB * NKP)            // 524288 total points
#define CIN 64
#define COUT 64
#define PM 8
#define HID 16
#define EPS 1e-5f

// ws float layout (moments padded: one 64B line per scalar -> independent atomics)
#define WS_MOM 0            // 14 slots x stride 16 floats
#define WS_A1 240           // 16: BN1 folded scale
#define WS_B1 256           // 16: BN1 folded shift
#define WS_A2 288           // 64: BN2 folded scale
#define WS_B2 352           // 64: BN2 folded shift
#define WS_PSUM 416         // 32 slots x 64: out channel sum partials
#define WS_PSQ 2464         // 32 slots x 64: out channel sumsq partials
#define WS_ZERO_FLOATS 4512
#define WS_WBT 4608         // bf16 wbT[512][64] as ushort (64 KB)

typedef __attribute__((ext_vector_type(8))) short short8;
typedef __attribute__((ext_vector_type(4))) float float4v;
typedef unsigned int uint32;
typedef unsigned short ushort16;

// fp32 -> bf16 round-half-up
static __device__ __forceinline__ ushort16 f2bf(float v) {
  uint32 u = __builtin_bit_cast(uint32, v);
  return (ushort16)((u + 0x8000u) >> 16);
}

// ---------------------------------------------------------------------------
// Kernel 1: moments of [x,y,z,||xyz||]. float4 loads (4 pts/iter), 256 blocks,
// wave shfl-reduce -> LDS block-reduce -> 1 atomic/scalar/block to padded lines.
// ---------------------------------------------------------------------------
#define MOMB 256
__global__ __launch_bounds__(256) void k_xyz_moments(
    const float* __restrict__ gx, float* __restrict__ ws) {
  float s[14];
#pragma unroll
  for (int i = 0; i < 14; ++i) s[i] = 0.f;
  int idx = blockIdx.x * 256 + threadIdx.x;  // 0..65535 (float4-group id)
#pragma unroll
  for (int it = 0; it < PTOT / 4 / (MOMB * 256); ++it) {  // 2 iters
    int g = idx + it * (MOMB * 256);
    int b = g >> 15;           // NKP/4 = 32768 groups per batch
    int r4 = g & 32767;
    const float* base = gx + (size_t)b * 3 * NKP + (size_t)r4 * 4;
    float4 X = *(const float4*)base;
    float4 Y = *(const float4*)(base + NKP);
    float4 Z = *(const float4*)(base + 2 * NKP);
    float px[4] = {X.x, X.y, X.z, X.w};
    float py[4] = {Y.x, Y.y, Y.z, Y.w};
    float pz[4] = {Z.x, Z.y, Z.z, Z.w};
#pragma unroll
    for (int e = 0; e < 4; ++e) {
      float v[4];
      v[0] = px[e];
      v[1] = py[e];
      v[2] = pz[e];
      v[3] = sqrtf(v[0] * v[0] + v[1] * v[1] + v[2] * v[2]);
#pragma unroll
      for (int j = 0; j < 4; ++j) s[j] += v[j];
      int ii = 4;
#pragma unroll
      for (int j = 0; j < 4; ++j)
#pragma unroll
        for (int l = j; l < 4; ++l) s[ii++] += v[j] * v[l];
    }
  }
#pragma unroll
  for (int i = 0; i < 14; ++i) {
    float x = s[i];
#pragma unroll
    for (int off = 32; off > 0; off >>= 1) x += __shfl_down(x, off, 64);
    s[i] = x;
  }
  __shared__ float red[4][14];
  int wave = threadIdx.x >> 6;
  if ((threadIdx.x & 63) == 0) {
#pragma unroll
    for (int i = 0; i < 14; ++i) red[wave][i] = s[i];
  }
  __syncthreads();
  if (threadIdx.x < 14) {
    float v = red[0][threadIdx.x] + red[1][threadIdx.x] +
              red[2][threadIdx.x] + red[3][threadIdx.x];
    atomicAdd(&ws[WS_MOM + threadIdx.x * 16], v);
  }
}

// ---------------------------------------------------------------------------
// Kernel 2: wb (64x512 fp32) -> wbT bf16 [col=512][ci=64].
// ---------------------------------------------------------------------------
__global__ __launch_bounds__(256) void k_wbt(const float* __restrict__ wb,
                                             ushort16* __restrict__ wbt) {
  int idx = blockIdx.x * 256 + threadIdx.x;  // ci*512 + col
  int ci = idx >> 9;
  int col = idx & 511;
  wbt[col * 64 + ci] = f2bf(wb[idx]);
}

// ---------------------------------------------------------------------------
// Kernel 3: fold BN1 -> alpha1/beta1.
// ---------------------------------------------------------------------------
__global__ void k_finalize1(const float* __restrict__ ws,
                            const float* __restrict__ w1,
                            const float* __restrict__ g1,
                            const float* __restrict__ b1,
                            float* __restrict__ out_ws) {
  int c = threadIdx.x;
  if (c >= HID) return;
  const float invP = 1.f / (float)PTOT;
  float mu[4];
#pragma unroll
  for (int j = 0; j < 4; ++j) mu[j] = ws[WS_MOM + j * 16] * invP;
  float S[4][4];
  int idx = 4;
#pragma unroll
  for (int j = 0; j < 4; ++j)
#pragma unroll
    for (int l = j; l < 4; ++l) {
      float v = ws[WS_MOM + idx * 16] * invP;
      ++idx;
      S[j][l] = v;
      S[l][j] = v;
    }
  float w[4];
#pragma unroll
  for (int j = 0; j < 4; ++j) w[j] = w1[c * 4 + j];
  float mean = 0.f;
#pragma unroll
  for (int j = 0; j < 4; ++j) mean += w[j] * mu[j];
  float Et2 = 0.f;
#pragma unroll
  for (int j = 0; j < 4; ++j)
#pragma unroll
    for (int l = 0; l < 4; ++l) Et2 += w[j] * w[l] * S[j][l];
  float var = Et2 - mean * mean;
  float a = g1[c] * rsqrtf(var + EPS);
  out_ws[WS_A1 + c] = a;
  out_ws[WS_B1 + c] = b1[c] - a * mean;
}

// ---------------------------------------------------------------------------
// Kernel 4: main MFMA kernel, restructured (round-4):
//  - NO feat LDS staging / NO pre-loop barrier: A-fragments loaded straight
//    from global into fp32 regs (16 dword loads, deep MLP), score-scaled and
//    packed to bf16 per m.
//  - ScoreNet computed lane-redundantly (q4 duplicates) -> sc[] lane-private.
//  - wave tile 16p x 64c; block 64p; grid 8192; LDS only for out transpose
//    (pitch 67 -> <=2-way banks) + stats. ~19 KB -> ~5 blocks/CU.
// ---------------------------------------------------------------------------
#define PPB 64

__global__ __launch_bounds__(256, 5) void k_main_mfma(
    const float* __restrict__ gx, const float* __restrict__ feat,
    const float* __restrict__ w1, const float* __restrict__ w2,
    const float* __restrict__ b2, const ushort16* __restrict__ wbt,
    float* __restrict__ ws, float* __restrict__ out) {
  __shared__ float outst[64 * 67];   // 17152 B
  __shared__ float sstat[4][64];
  __shared__ float qstat[4][64];

  const int t = threadIdx.x;
  const int w = t >> 6;
  const int L = t & 63;
  const int l16 = L & 15;
  const int q4 = L >> 4;

  const int pblk = blockIdx.x * PPB;
  const int b = pblk >> 17;
  const int r0 = pblk & (NKP - 1);
  const int rw = r0 + w * 16;        // wave p-base within batch

  // ---- ScoreNet (each lane computes its own row-point p = rw + l16)
  float sc[PM];
  {
    const float* gb = gx + (size_t)b * 3 * NKP + rw + l16;
    float x = gb[0], y = gb[NKP], z = gb[2 * NKP];
    float ed = sqrtf(x * x + y * y + z * z);
    float h[HID];
#pragma unroll
    for (int c = 0; c < HID; ++c) {
      float tv = w1[c * 4 + 0] * x + w1[c * 4 + 1] * y + w1[c * 4 + 2] * z +
                 w1[c * 4 + 3] * ed;
      h[c] = fmaxf(ws[WS_A1 + c] * tv + ws[WS_B1 + c], 0.f);
    }
    float s[PM];
#pragma unroll
    for (int m = 0; m < PM; ++m) {
      float a = b2[m];
#pragma unroll
      for (int c = 0; c < HID; ++c) a += w2[m * HID + c] * h[c];
      s[m] = a;
    }
    float mx = s[0];
#pragma unroll
    for (int m = 1; m < PM; ++m) mx = fmaxf(mx, s[m]);
    float esum = 0.f;
#pragma unroll
    for (int m = 0; m < PM; ++m) {
      s[m] = __expf(s[m] - mx);
      esum += s[m];
    }
    float inv = 1.f / (1.f + esum);
#pragma unroll
    for (int m = 0; m < PM; ++m) sc[m] = s[m] * inv;
  }

  // ---- A-operand feat values, straight from global (fp32, MFMA A-layout:
  //      row p = l16, k ci = ks*32 + q4*8 + j)
  float ff[2][8];
  {
    const float* fb = feat + (size_t)b * CIN * NKP + rw + l16;
#pragma unroll
    for (int ks = 0; ks < 2; ++ks)
#pragma unroll
      for (int j = 0; j < 8; ++j)
        ff[ks][j] = fb[(size_t)(ks * 32 + q4 * 8 + j) * NKP];
  }

  float4v acc[4];
#pragma unroll
  for (int ct = 0; ct < 4; ++ct) acc[ct] = (float4v)0.f;

  // ---- m loop: scale A by sc[m], MFMA vs wbT m-slice (L1/L2-resident 64 KB)
#pragma unroll
  for (int m = 0; m < PM; ++m) {
    short8 bf[2][4];
#pragma unroll
    for (int ks = 0; ks < 2; ++ks)
#pragma unroll
      for (int ct = 0; ct < 4; ++ct) {
        int col = m * 64 + ct * 16 + l16;
        bf[ks][ct] = *(const short8*)(wbt + col * 64 + ks * 32 + q4 * 8);
      }
    float sm = sc[m];
    short8 au[2];
#pragma unroll
    for (int ks = 0; ks < 2; ++ks) {
      union { short8 v; uint32 u[4]; } pk;
#pragma unroll
      for (int e = 0; e < 4; ++e) {
        uint32 u0 = __builtin_bit_cast(uint32, ff[ks][2 * e] * sm) + 0x8000u;
        uint32 u1 =
            __builtin_bit_cast(uint32, ff[ks][2 * e + 1] * sm) + 0x8000u;
        pk.u[e] = __builtin_amdgcn_perm(u1, u0, 0x07060302u);
      }
      au[ks] = pk.v;
    }
#pragma unroll
    for (int ks = 0; ks < 2; ++ks)
#pragma unroll
      for (int ct = 0; ct < 4; ++ct)
        acc[ct] = __builtin_amdgcn_mfma_f32_16x16x32_bf16(au[ks], bf[ks][ct],
                                                          acc[ct], 0, 0, 0);
  }

  // ---- BN2 stats: lane holds c = l16 + 16ct, rows p = q4*4+r; reduce q4
#pragma unroll
  for (int ct = 0; ct < 4; ++ct) {
    float s = 0.f, q = 0.f;
#pragma unroll
    for (int r = 0; r < 4; ++r) {
      float v = acc[ct][r];
      s += v;
      q += v * v;
    }
    s += __shfl_xor(s, 16, 64);
    q += __shfl_xor(q, 16, 64);
    s += __shfl_xor(s, 32, 64);
    q += __shfl_xor(q, 32, 64);
    if (L < 16) {
      sstat[w][ct * 16 + L] = s;
      qstat[w][ct * 16 + L] = q;
    }
  }

  // ---- stage out tile [p][c] in LDS (C-layout: p = 16w + 4q4 + r, c = 16ct+l16)
#pragma unroll
  for (int ct = 0; ct < 4; ++ct)
#pragma unroll
    for (int r = 0; r < 4; ++r)
      outst[(w * 16 + q4 * 4 + r) * 67 + ct * 16 + l16] = acc[ct][r];
  __syncthreads();

  // ---- block stats -> spread atomic partials
  if (t < COUT) {
    float s = sstat[0][t] + sstat[1][t] + sstat[2][t] + sstat[3][t];
    float q = qstat[0][t] + qstat[1][t] + qstat[2][t] + qstat[3][t];
    int slot = blockIdx.x & 31;
    atomicAdd(&ws[WS_PSUM + slot * 64 + t], s);
    atomicAdd(&ws[WS_PSQ + slot * 64 + t], q);
  }

  // ---- coalesced pre-BN store (256 B per c-row per wave-iter)
  float* ob = out + (size_t)b * COUT * NKP + r0;
#pragma unroll
  for (int i = 0; i < 16; ++i) {
    int flat = i * 256 + t;
    int c = flat >> 6;
    int p = flat & 63;
    ob[(size_t)c * NKP + p] = outst[p * 67 + c];
  }
}

// ---------------------------------------------------------------------------
// Kernel 5: fold BN2 (reduce 32 partial slots).
// ---------------------------------------------------------------------------
__global__ void k_finalize2(const float* __restrict__ ws,
                            const float* __restrict__ g_out,
                            const float* __restrict__ b_out,
                            float* __restrict__ out_ws) {
  int c = threadIdx.x;
  if (c >= COUT) return;
  float s = 0.f, q = 0.f;
  for (int sl = 0; sl < 32; ++sl) {
    s += ws[WS_PSUM + sl * 64 + c];
    q += ws[WS_PSQ + sl * 64 + c];
  }
  const float invP = 1.f / (float)PTOT;
  float mean = s * invP;
  float var = q * invP - mean * mean;
  float a = g_out[c] * rsqrtf(var + EPS);
  out_ws[WS_A2 + c] = a;
  out_ws[WS_B2 + c] = b_out[c] - a * mean;
}

// ---------------------------------------------------------------------------
// Kernel 6: in-place normalize + ReLU.
// ---------------------------------------------------------------------------
__global__ __launch_bounds__(256) void k_norm(float* __restrict__ out,
                                              const float* __restrict__ ws) {
  size_t i4 = (size_t)blockIdx.x * 256 + threadIdx.x;
  size_t elem = i4 * 4;
  int c = (int)((elem >> 17) & 63);
  float a = ws[WS_A2 + c];
  float bb = ws[WS_B2 + c];
  float4* p = (float4*)out;
  float4 v = p[i4];
  v.x = fmaxf(a * v.x + bb, 0.f);
  v.y = fmaxf(a * v.y + bb, 0.f);
  v.z = fmaxf(a * v.z + bb, 0.f);
  v.w = fmaxf(a * v.w + bb, 0.f);
  p[i4] = v;
}

extern "C" void kernel_launch(void* const* d_in, const int* in_sizes, int n_in,
                              void* d_out, int out_size, void* d_ws,
                              size_t ws_size, hipStream_t stream) {
  const float* gx = (const float*)d_in[0];
  const float* feat = (const float*)d_in[1];
  const float* w1 = (const float*)d_in[2];
  const float* g1 = (const float*)d_in[3];
  const float* b1 = (const float*)d_in[4];
  const float* w2 = (const float*)d_in[5];
  const float* b2 = (const float*)d_in[6];
  const float* wb = (const float*)d_in[7];
  const float* g_out = (const float*)d_in[8];
  const float* b_out = (const float*)d_in[9];
  float* out = (float*)d_out;
  float* ws = (float*)d_ws;
  ushort16* wbt = (ushort16*)(ws + WS_WBT);

  (void)in_sizes; (void)n_in; (void)out_size; (void)ws_size;

  hipMemsetAsync(d_ws, 0, WS_ZERO_FLOATS * sizeof(float), stream);

  k_xyz_moments<<<MOMB, 256, 0, stream>>>(gx, ws);
  k_wbt<<<128, 256, 0, stream>>>(wb, wbt);
  k_finalize1<<<1, 64, 0, stream>>>(ws, w1, g1, b1, ws);
  k_main_mfma<<<PTOT / PPB, 256, 0, stream>>>(gx, feat, w1, w2, b2, wbt, ws,
                                              out);
  k_finalize2<<<1, 64, 0, stream>>>(ws, g_out, b_out, ws);
  k_norm<<<(PTOT * COUT / 4) / 256, 256, 0, stream>>>(out, ws);
}